// Round 13
// baseline (413.987 us; speedup 1.0000x reference)
//
#include <hip/hip_runtime.h>
#include <cstdio>
#include <cstdint>

#define S_TOK 4096
#define CDIM  1024
#define EXP   8
#define HRAW  2744
#define HPAD  2816
#define MAXROWS  14336   // 56 tiles * 256 (build pads segments to 256)
#define MAXTILES 112     // 128-row tiles
#define MAXT2    56      // 256-row tiles
#define NSLICE1  (HPAD / 128)   // 22
#define G1_BLKS  (MAXTILES * NSLICE1)  // 2464 (divisible by 8)
#define G2_BLKS  (MAXT2 * 4)           // 224 (divisible by 8)
#define NT2K     (HPAD / 64)           // 44

typedef __attribute__((ext_vector_type(8))) short bf16x8;
typedef __attribute__((ext_vector_type(4))) float f32x4;
typedef __attribute__((ext_vector_type(4))) unsigned short us4;
typedef __attribute__((ext_vector_type(8))) unsigned short us8;
typedef unsigned short us;

__device__ __forceinline__ us f2bf(float f) {
  unsigned u = __float_as_uint(f);
  u += 0x7fffu + ((u >> 16) & 1u);
  return (us)(u >> 16);
}
__device__ __forceinline__ float bf2f(us v) {
  return __uint_as_float((unsigned)v << 16);
}

__device__ __forceinline__ void gl16(const us* g, us* l) {
  __builtin_amdgcn_global_load_lds((__attribute__((address_space(1))) void*)g,
                                   (__attribute__((address_space(3))) void*)l,
                                   16, 0, 0);
}

// bijective XCD swizzle (m204)
__device__ __forceinline__ int xcd_swz(int orig, int nwg) {
  int q = nwg >> 3, r = nwg & 7;
  int x = orig & 7, idx = orig >> 3;
  return (x < r ? x * (q + 1) : r * (q + 1) + (x - r) * q) + idx;
}

// ---------------- conversion helpers (fp32 -> bf16, padded, 16B stores) --------
#define CH8_RP1  (HPAD * CDIM / 8)
#define CH8_CPR  (HPAD / 8)

__device__ __forceinline__ void cvt8_rowpad(const float* __restrict__ src,
                                            us* __restrict__ dst, int idx) {
  int m = idx / CH8_RP1, rem = idx - m * CH8_RP1;
  int r = rem >> 7, c8 = rem & 127;
  us8 o;
  if (r < HRAW) {
    const float4* p = (const float4*)(src + ((size_t)(m * HRAW + r) * CDIM + c8 * 8));
    float4 v0 = p[0], v1 = p[1];
    o[0] = f2bf(v0.x); o[1] = f2bf(v0.y); o[2] = f2bf(v0.z); o[3] = f2bf(v0.w);
    o[4] = f2bf(v1.x); o[5] = f2bf(v1.y); o[6] = f2bf(v1.z); o[7] = f2bf(v1.w);
  } else {
    o[0] = 0; o[1] = 0; o[2] = 0; o[3] = 0; o[4] = 0; o[5] = 0; o[6] = 0; o[7] = 0;
  }
  *(us8*)(dst + ((size_t)(m * HPAD + r) * CDIM + c8 * 8)) = o;
}

__device__ __forceinline__ void cvt8_colpad(const float* __restrict__ src,
                                            us* __restrict__ dst, int idx) {
  int r = idx / CH8_CPR, c8 = idx - r * CH8_CPR;
  int c = c8 * 8;
  us8 o;
  if (c < HRAW) {
    const float4* p = (const float4*)(src + (size_t)r * HRAW + c);
    float4 v0 = p[0], v1 = p[1];
    o[0] = f2bf(v0.x); o[1] = f2bf(v0.y); o[2] = f2bf(v0.z); o[3] = f2bf(v0.w);
    o[4] = f2bf(v1.x); o[5] = f2bf(v1.y); o[6] = f2bf(v1.z); o[7] = f2bf(v1.w);
  } else {
    o[0] = 0; o[1] = 0; o[2] = 0; o[3] = 0; o[4] = 0; o[5] = 0; o[6] = 0; o[7] = 0;
  }
  *(us8*)(dst + (size_t)r * HPAD + c) = o;
}

// ---------------- gating (standalone, first) ----------------
__global__ void __launch_bounds__(256) gate_kernel(const float* __restrict__ x,
                                                   const float* __restrict__ gw,
                                                   us* __restrict__ xb,
                                                   int* __restrict__ tki,
                                                   float* __restrict__ tkw,
                                                   float* __restrict__ probs) {
  const int wv = threadIdx.x >> 6, lane = threadIdx.x & 63;
  const int s = blockIdx.x * 4 + wv;
  const float4* xs4 = (const float4*)(x + (size_t)s * CDIM);
  float acc[8] = {0, 0, 0, 0, 0, 0, 0, 0};
#pragma unroll
  for (int j = 0; j < 4; j++) {
    float4 v = xs4[lane * 4 + j];
    int c = lane * 16 + j * 4;
    us4 ov;
    ov.x = f2bf(v.x); ov.y = f2bf(v.y); ov.z = f2bf(v.z); ov.w = f2bf(v.w);
    *(us4*)(xb + (size_t)s * CDIM + c) = ov;
#pragma unroll
    for (int ee = 0; ee < 8; ee++) {
      const float* g = gw + ee * CDIM + c;
      acc[ee] += v.x * g[0] + v.y * g[1] + v.z * g[2] + v.w * g[3];
    }
  }
#pragma unroll
  for (int ee = 0; ee < 8; ee++) {
#pragma unroll
    for (int off = 32; off > 0; off >>= 1) acc[ee] += __shfl_xor(acc[ee], off, 64);
  }
  if (lane == 0) {
    float mx = acc[0];
    for (int ee = 1; ee < 8; ee++) mx = fmaxf(mx, acc[ee]);
    float p[8], sm = 0.f;
    for (int ee = 0; ee < 8; ee++) { p[ee] = expf(acc[ee] - mx); sm += p[ee]; }
    float inv = 1.f / sm;
    for (int ee = 0; ee < 8; ee++) probs[s * 8 + ee] = p[ee] * inv;
    int i0 = 0; float b0 = p[0];
    for (int ee = 1; ee < 8; ee++) if (p[ee] > b0) { b0 = p[ee]; i0 = ee; }
    int i1 = -1; float b1 = -1.f;
    for (int ee = 0; ee < 8; ee++) if (ee != i0 && p[ee] > b1) { b1 = p[ee]; i1 = ee; }
    float rw0 = b0 * inv, rw1 = b1 * inv;
    float den = 1.f / (rw0 + rw1);
    tki[2 * s] = i0; tki[2 * s + 1] = i1;
    tkw[2 * s] = rw0 * den; tkw[2 * s + 1] = rw1 * den;
  }
}

// ---------------- cvt(w1,w2,sw1,sw2) with build fused as block 0 ----------------
#define CVTAB_BLKS 2048
#define AB8_W1   (8 * CH8_RP1)
#define AB8_W2   (AB8_W1 + 8 * CH8_RP1)
#define AB8_SW1  (AB8_W2 + CH8_RP1)
#define AB8_SW2  (AB8_SW1 + CH8_RP1)

__global__ void __launch_bounds__(512) cvtab_build_kernel(
    const float* __restrict__ w1, const float* __restrict__ w2,
    const float* __restrict__ sw1, const float* __restrict__ sw2,
    us* __restrict__ w1b, us* __restrict__ w2b,
    us* __restrict__ sw1b, us* __restrict__ sw2b,
    const int* __restrict__ tki, const float* __restrict__ tkw,
    const float* __restrict__ probs, int* __restrict__ meta,
    int* __restrict__ pairtok, float* __restrict__ pairw,
    int* __restrict__ invmap, int* __restrict__ tile_expert,
    float* __restrict__ aux_out) {
  if (blockIdx.x == 0) {
    const int tid = threadIdx.x, lane = tid & 63, wv = tid >> 6;
    __shared__ int s_cnt[EXP];
    __shared__ int s_amc[EXP];
    __shared__ float s_imp[EXP];
    {
      const int e = wv;
      int c_cnt = 0, c_amc = 0;
      float imp = 0.f;
      for (int s0 = 0; s0 < S_TOK; s0 += 64) {
        int s = s0 + lane;
        int i0 = tki[2 * s], i1 = tki[2 * s + 1];
        c_cnt += (i0 == e) || (i1 == e);
        c_amc += (i0 == e);
        imp += probs[s * 8 + e];
      }
#pragma unroll
      for (int off = 32; off > 0; off >>= 1) {
        c_cnt += __shfl_xor(c_cnt, off, 64);
        c_amc += __shfl_xor(c_amc, off, 64);
        imp   += __shfl_xor(imp, off, 64);
      }
      if (lane == 0) { s_cnt[e] = c_cnt; s_amc[e] = c_amc; s_imp[e] = imp; }
    }
    __syncthreads();
    int pad[EXP], start[EXP];
    int o = S_TOK;
#pragma unroll
    for (int j = 0; j < EXP; j++) {
      pad[j] = ((s_cnt[j] + 255) >> 8) << 8;   // 256-aligned segments (gemm2 BM=256)
      start[j] = o;
      o += pad[j];
    }
    const int total = o;
    for (int r = tid; r < S_TOK; r += 512) { pairtok[r] = r; pairw[r] = 1.f; }
    {
      const int e = wv;
      int base = start[e];
      for (int s0 = 0; s0 < S_TOK; s0 += 64) {
        int s = s0 + lane;
        int i0 = tki[2 * s], i1 = tki[2 * s + 1];
        bool m0 = (i0 == e), m1 = (i1 == e);
        bool mm = m0 || m1;
        unsigned long long mk = __ballot(mm);
        if (mm) {
          int pos = base + __popcll(mk & ((1ull << lane) - 1ull));
          pairtok[pos] = s;
          pairw[pos] = m0 ? tkw[2 * s] : tkw[2 * s + 1];
          invmap[2 * s + (m0 ? 0 : 1)] = pos;
        }
        base += __popcll(mk);
      }
      for (int r = base + lane; r < start[e] + pad[e]; r += 64) {
        pairtok[r] = -1; pairw[r] = 0.f;
      }
    }
    if (tid < 128) {
      int ex = 8;
      if (tid >= 32) {
        int rr = tid * 128;
#pragma unroll
        for (int j = 0; j < EXP; j++)
          if (rr >= start[j] && rr < start[j] + pad[j]) ex = j;
      }
      tile_expert[tid] = ex;
    }
    if (tid == 0) {
      meta[0] = total >> 7;   // count of 128-tiles (even, since total is 256-mult)
      float a = 0.f;
      for (int j = 0; j < EXP; j++)
        a += (s_imp[j] * (1.f / 4096.f)) * ((float)s_amc[j] * (1.f / 4096.f));
      aux_out[0] = 8.f * a;
    }
    return;
  }
  for (int i = (blockIdx.x - 1) * 512 + threadIdx.x; i < AB8_SW2;
       i += (CVTAB_BLKS - 1) * 512) {
    if (i < AB8_W1)       cvt8_rowpad(w1,  w1b,  i);
    else if (i < AB8_W2)  cvt8_rowpad(w2,  w2b,  i - AB8_W1);
    else if (i < AB8_SW1) cvt8_rowpad(sw1, sw1b, i - AB8_W2);
    else                  cvt8_rowpad(sw2, sw2b, i - AB8_SW1);
  }
}

// ---------------- GEMM1: BK=64 single-buffer + w3/sw3 cvt tail blocks ----------
#define W3CVT_BLKS 1024
#define W38_CHUNKS (8 * CDIM * CH8_CPR)
#define W38_TOT    (W38_CHUNKS + CDIM * CH8_CPR)

__global__ void __launch_bounds__(256, 2) gemm1_kernel(
    const us* __restrict__ xb, const us* __restrict__ w1b, const us* __restrict__ w2b,
    const us* __restrict__ sw1b, const us* __restrict__ sw2b,
    const int* __restrict__ pairtok, const int* __restrict__ tile_expert,
    const int* __restrict__ meta, us* __restrict__ h,
    const float* __restrict__ w3, const float* __restrict__ sw3,
    us* __restrict__ w3b, us* __restrict__ sw3b) {
  if (blockIdx.x >= G1_BLKS) {
    for (int i = (blockIdx.x - G1_BLKS) * 256 + threadIdx.x; i < W38_TOT;
         i += W3CVT_BLKS * 256) {
      if (i < W38_CHUNKS) cvt8_colpad(w3,  w3b,  i);
      else                cvt8_colpad(sw3, sw3b, i - W38_CHUNKS);
    }
    return;
  }
  const int wgid = xcd_swz(blockIdx.x, G1_BLKS);
  const int mt = wgid % MAXTILES;
  if (mt >= meta[0]) return;
  const int row0 = mt * 128;
  if (pairtok[row0] < 0) return;   // fully-padded tile (padding is at segment tail)
  const int n0 = (wgid / MAXTILES) * 128;
  const int e = tile_expert[mt];
  const us* B1 = (e == 8) ? sw1b : (w1b + (size_t)e * HPAD * CDIM);
  const us* B2 = (e == 8) ? sw2b : (w2b + (size_t)e * HPAD * CDIM);
  __shared__ __align__(16) us sA[128 * 64];
  __shared__ __align__(16) us sB1[128 * 64];
  __shared__ __align__(16) us sB2[128 * 64];
  const int tid = threadIdx.x, lane = tid & 63;
  const int wm = tid >> 7, wn = (tid >> 6) & 1;
  const int srow = tid >> 3;
  const int soct = (tid & 7) ^ (srow & 7);
  const us* gA[4];
  const us* gB1a[4];
  const us* gB2a[4];
#pragma unroll
  for (int j = 0; j < 4; j++) {
    int t = pairtok[row0 + j * 32 + srow]; if (t < 0) t = 0;
    gA[j]   = xb + (size_t)t * CDIM + soct * 8;
    gB1a[j] = B1 + (size_t)(n0 + j * 32 + srow) * CDIM + soct * 8;
    gB2a[j] = B2 + (size_t)(n0 + j * 32 + srow) * CDIM + soct * 8;
  }
  f32x4 au[4][4], av[4][4];
#pragma unroll
  for (int m = 0; m < 4; m++)
#pragma unroll
    for (int n = 0; n < 4; n++)
#pragma unroll
      for (int r = 0; r < 4; r++) { au[m][n][r] = 0.f; av[m][n][r] = 0.f; }

  const int rl = lane & 15, fo = lane >> 4;
  const int x0 = ((0 + fo) ^ (rl & 7)) << 3;
  const int x1 = ((4 + fo) ^ (rl & 7)) << 3;
  for (int k0 = 0; k0 < CDIM; k0 += 64) {
#pragma unroll
    for (int j = 0; j < 4; j++) {
      gl16(gA[j] + k0,   &sA[(j * 256 + tid) * 8]);
      gl16(gB1a[j] + k0, &sB1[(j * 256 + tid) * 8]);
      gl16(gB2a[j] + k0, &sB2[(j * 256 + tid) * 8]);
    }
    __syncthreads();
#pragma unroll
    for (int ks = 0; ks < 2; ks++) {
      const int kx = ks ? x1 : x0;
      bf16x8 a[4], b1[4], b2[4];
#pragma unroll
      for (int m = 0; m < 4; m++)
        a[m] = *(const bf16x8*)&sA[(wm * 64 + m * 16 + rl) * 64 + kx];
#pragma unroll
      for (int n = 0; n < 4; n++) {
        b1[n] = *(const bf16x8*)&sB1[(wn * 64 + n * 16 + rl) * 64 + kx];
        b2[n] = *(const bf16x8*)&sB2[(wn * 64 + n * 16 + rl) * 64 + kx];
      }
#pragma unroll
      for (int m = 0; m < 4; m++)
#pragma unroll
        for (int n = 0; n < 4; n++) {
          au[m][n] = __builtin_amdgcn_mfma_f32_16x16x32_bf16(a[m], b1[n], au[m][n], 0, 0, 0);
          av[m][n] = __builtin_amdgcn_mfma_f32_16x16x32_bf16(a[m], b2[n], av[m][n], 0, 0, 0);
        }
    }
    __syncthreads();
  }
  const int rb = (lane >> 4) * 4, cb = lane & 15;
#pragma unroll
  for (int m = 0; m < 4; m++)
#pragma unroll
    for (int n = 0; n < 4; n++)
#pragma unroll
      for (int r = 0; r < 4; r++) {
        int row = row0 + wm * 64 + m * 16 + rb + r;
        int col = n0 + wn * 64 + n * 16 + cb;
        float u = au[m][n][r], v = av[m][n][r];
        float sg = 1.f / (1.f + __expf(-u));
        h[(size_t)row * HPAD + col] = f2bf(u * sg * v);
      }
}

// ---------------- GEMM2: 256x256 4-phase/K-tile pipelined, bf16 out ------------
// 512 thr / 8 waves (wm in {0,1} x wn in {0..3}); per-wave out 128x64.
// BK=64, double-buffered 128 KB LDS. Per phase: 8 ds_read_b128 + 2 gl16 stage
// (next K-tile, other slot) -> lgkmcnt(0)+sched_barrier -> setprio(1)+16 MFMA
// -> barrier. K-tile boundary: vmcnt(0)+barrier (loads had 4 phases of flight).
__global__ void __launch_bounds__(512, 2) gemm2_kernel(
    const us* __restrict__ h, const us* __restrict__ w3b, const us* __restrict__ sw3b,
    const int* __restrict__ pairtok, const int* __restrict__ tile_expert,
    const int* __restrict__ meta, us* __restrict__ eo) {
  const int wgid = xcd_swz(blockIdx.x, G2_BLKS);
  const int mt2 = wgid % MAXT2;
  if (2 * mt2 >= meta[0]) return;
  const int row0 = mt2 * 256;
  if (pairtok[row0] < 0) return;   // whole 256-tile is padding
  const int n0 = (wgid / MAXT2) * 256;
  const int e = tile_expert[2 * mt2];
  const us* B = (e == 8) ? sw3b : (w3b + (size_t)e * CDIM * HPAD);
  __shared__ __align__(16) us sA[2][256 * 64];
  __shared__ __align__(16) us sB[2][256 * 64];
  const int tid = threadIdx.x, lane = tid & 63;
  const int wid = tid >> 6, wm = wid >> 2, wn = wid & 3;
  const int srow = tid >> 3;
  const int soct = (tid & 7) ^ (srow & 7);
  const us* gA[4];
  const us* gB[4];
#pragma unroll
  for (int j = 0; j < 4; j++) {
    gA[j] = h + (size_t)(row0 + j * 64 + srow) * HPAD + soct * 8;
    gB[j] = B + (size_t)(n0 + j * 64 + srow) * HPAD + soct * 8;
  }
  f32x4 ac[8][4];
#pragma unroll
  for (int m = 0; m < 8; m++)
#pragma unroll
    for (int n = 0; n < 4; n++)
#pragma unroll
      for (int r = 0; r < 4; r++) ac[m][n][r] = 0.f;

  const int rl = lane & 15, fo = lane >> 4;
  // prologue: stage K-tile 0 into slot 0
#pragma unroll
  for (int j = 0; j < 4; j++) {
    gl16(gA[j], &sA[0][j * 4096 + tid * 8]);
    gl16(gB[j], &sB[0][j * 4096 + tid * 8]);
  }
  asm volatile("s_waitcnt vmcnt(0)" ::: "memory");
  __builtin_amdgcn_s_barrier();
#pragma unroll 1
  for (int t = 0; t < NT2K; t++) {
    const int slot = t & 1;
    const int k1 = (t + 1) * 64;
    const us* pa = sA[slot];
    const us* pb = sB[slot];
#pragma unroll
    for (int p = 0; p < 4; p++) {
      const int ks = p >> 1, mh = p & 1;
      const int kx = (((ks << 2) + fo) ^ (rl & 7)) << 3;
      bf16x8 a[4], b[4];
#pragma unroll
      for (int m = 0; m < 4; m++)
        a[m] = *(const bf16x8*)&pa[(wm * 128 + mh * 64 + m * 16 + rl) * 64 + kx];
#pragma unroll
      for (int n = 0; n < 4; n++)
        b[n] = *(const bf16x8*)&pb[(wn * 64 + n * 16 + rl) * 64 + kx];
      if (t + 1 < NT2K) {
        gl16(gA[p] + k1, &sA[slot ^ 1][p * 4096 + tid * 8]);
        gl16(gB[p] + k1, &sB[slot ^ 1][p * 4096 + tid * 8]);
      }
      asm volatile("s_waitcnt lgkmcnt(0)" ::: "memory");
      __builtin_amdgcn_sched_barrier(0);
      __builtin_amdgcn_s_setprio(1);
#pragma unroll
      for (int m = 0; m < 4; m++)
#pragma unroll
        for (int n = 0; n < 4; n++)
          ac[mh * 4 + m][n] =
              __builtin_amdgcn_mfma_f32_16x16x32_bf16(a[m], b[n], ac[mh * 4 + m][n], 0, 0, 0);
      __builtin_amdgcn_s_setprio(0);
      __builtin_amdgcn_s_barrier();
    }
    // K-tile boundary: next tile's stages (issued over the 4 phases) must land.
    asm volatile("s_waitcnt vmcnt(0)" ::: "memory");
    __builtin_amdgcn_s_barrier();
  }
  const int rb = (lane >> 4) * 4, cb = lane & 15;
#pragma unroll
  for (int m = 0; m < 8; m++)
#pragma unroll
    for (int n = 0; n < 4; n++)
#pragma unroll
      for (int r = 0; r < 4; r++) {
        int row = row0 + wm * 128 + m * 16 + rb + r;
        int col = n0 + wn * 64 + n * 16 + cb;
        eo[(size_t)row * CDIM + col] = f2bf(ac[m][n][r]);
      }
}

// ---------------- combine (bf16 eo) ----------------
__global__ void __launch_bounds__(256) combine_kernel(const us* __restrict__ eo,
                                                      const int* __restrict__ invmap,
                                                      const float* __restrict__ pairw,
                                                      float* __restrict__ out) {
  const int s = blockIdx.x;
  const int c = threadIdx.x * 4;
  const int j0 = invmap[2 * s], j1 = invmap[2 * s + 1];
  const float w0 = pairw[j0], w1 = pairw[j1];
  us4 a = *(const us4*)(eo + (size_t)s * CDIM + c);
  us4 b = *(const us4*)(eo + (size_t)j0 * CDIM + c);
  us4 d = *(const us4*)(eo + (size_t)j1 * CDIM + c);
  float4 o;
  o.x = bf2f(a.x) + w0 * bf2f(b.x) + w1 * bf2f(d.x);
  o.y = bf2f(a.y) + w0 * bf2f(b.y) + w1 * bf2f(d.y);
  o.z = bf2f(a.z) + w0 * bf2f(b.z) + w1 * bf2f(d.z);
  o.w = bf2f(a.w) + w0 * bf2f(b.w) + w1 * bf2f(d.w);
  *(float4*)(out + (size_t)s * CDIM + c) = o;
}

extern "C" void kernel_launch(void* const* d_in, const int* in_sizes, int n_in,
                              void* d_out, int out_size, void* d_ws, size_t ws_size,
                              hipStream_t stream) {
  const float* x   = (const float*)d_in[0];
  const float* gw  = (const float*)d_in[1];
  const float* w1  = (const float*)d_in[2];
  const float* w2  = (const float*)d_in[3];
  const float* w3  = (const float*)d_in[4];
  const float* sw1 = (const float*)d_in[5];
  const float* sw2 = (const float*)d_in[6];
  const float* sw3 = (const float*)d_in[7];
  float* out = (float*)d_out;
  char* ws = (char*)d_ws;
  size_t off = 0;
  auto take = [&](size_t bytes) -> char* {
    char* p = ws + off;
    off = (off + bytes + 255) & ~(size_t)255;
    return p;
  };
  us* xb    = (us*)take((size_t)S_TOK * CDIM * 2);
  us* w1b   = (us*)take((size_t)EXP * HPAD * CDIM * 2);
  us* w2b   = (us*)take((size_t)EXP * HPAD * CDIM * 2);
  us* w3b   = (us*)take((size_t)EXP * CDIM * HPAD * 2);
  us* sw1b  = (us*)take((size_t)HPAD * CDIM * 2);
  us* sw2b  = (us*)take((size_t)HPAD * CDIM * 2);
  us* sw3b  = (us*)take((size_t)CDIM * HPAD * 2);
  us* hbuf  = (us*)take((size_t)MAXROWS * HPAD * 2);
  us* eo    = (us*)take((size_t)MAXROWS * CDIM * 2);
  int* pairtok = (int*)take(MAXROWS * 4);
  float* pairw = (float*)take(MAXROWS * 4);
  int* invmap  = (int*)take(S_TOK * 2 * 4);
  int* tile_expert = (int*)take(128 * 4);
  int* tki = (int*)take(S_TOK * 2 * 4);
  float* tkw = (float*)take(S_TOK * 2 * 4);
  float* probs = (float*)take(S_TOK * EXP * 4);
  int* meta = (int*)take(256);
  if (off > ws_size) {
    fprintf(stderr, "MoE kernel: ws too small, need %zu got %zu\n", off, ws_size);
    return;
  }
  gate_kernel<<<S_TOK / 4, 256, 0, stream>>>(x, gw, xb, tki, tkw, probs);
  cvtab_build_kernel<<<CVTAB_BLKS, 512, 0, stream>>>(
      w1, w2, sw1, sw2, w1b, w2b, sw1b, sw2b,
      tki, tkw, probs, meta, pairtok, pairw, invmap, tile_expert,
      out + (size_t)S_TOK * CDIM);
  gemm1_kernel<<<G1_BLKS + W3CVT_BLKS, 256, 0, stream>>>(
      xb, w1b, w2b, sw1b, sw2b, pairtok, tile_expert, meta, hbuf,
      w3, sw3, w3b, sw3b);
  gemm2_kernel<<<G2_BLKS, 512, 0, stream>>>(
      hbuf, w3b, sw3b, pairtok, tile_expert, meta, eo);
  combine_kernel<<<S_TOK, 256, 0, stream>>>(eo, invmap, pairw, out);
}

// Round 14
// 383.188 us; speedup vs baseline: 1.0804x; 1.0804x over previous
//
#include <hip/hip_runtime.h>
#include <cstdio>
#include <cstdint>

#define S_TOK 4096
#define CDIM  1024
#define EXP   8
#define HRAW  2744
#define HPAD  2816
#define MAXROWS  13312   // 104 tiles * 128
#define MAXTILES 104
#define NSLICE1  (HPAD / 128)   // 22
#define NSLICE2  (CDIM / 256)   // 4  (gemm2 block = 128x256)
#define G1_BLKS  (MAXTILES * NSLICE1)  // 2288 (divisible by 8)

typedef __attribute__((ext_vector_type(8))) short bf16x8;
typedef __attribute__((ext_vector_type(4))) float f32x4;
typedef __attribute__((ext_vector_type(4))) unsigned short us4;
typedef __attribute__((ext_vector_type(8))) unsigned short us8;
typedef unsigned short us;

__device__ __forceinline__ us f2bf(float f) {
  unsigned u = __float_as_uint(f);
  u += 0x7fffu + ((u >> 16) & 1u);
  return (us)(u >> 16);
}
__device__ __forceinline__ float bf2f(us v) {
  return __uint_as_float((unsigned)v << 16);
}

__device__ __forceinline__ void gl16(const us* g, us* l) {
  __builtin_amdgcn_global_load_lds((__attribute__((address_space(1))) void*)g,
                                   (__attribute__((address_space(3))) void*)l,
                                   16, 0, 0);
}

// bijective XCD swizzle (m204)
__device__ __forceinline__ int xcd_swz(int orig, int nwg) {
  int q = nwg >> 3, r = nwg & 7;
  int x = orig & 7, idx = orig >> 3;
  return (x < r ? x * (q + 1) : r * (q + 1) + (x - r) * q) + idx;
}

// ---------------- conversion helpers (fp32 -> bf16, padded, 16B stores) --------
#define CH8_RP1  (HPAD * CDIM / 8)
#define CH8_CPR  (HPAD / 8)

__device__ __forceinline__ void cvt8_rowpad(const float* __restrict__ src,
                                            us* __restrict__ dst, int idx) {
  int m = idx / CH8_RP1, rem = idx - m * CH8_RP1;
  int r = rem >> 7, c8 = rem & 127;
  us8 o;
  if (r < HRAW) {
    const float4* p = (const float4*)(src + ((size_t)(m * HRAW + r) * CDIM + c8 * 8));
    float4 v0 = p[0], v1 = p[1];
    o[0] = f2bf(v0.x); o[1] = f2bf(v0.y); o[2] = f2bf(v0.z); o[3] = f2bf(v0.w);
    o[4] = f2bf(v1.x); o[5] = f2bf(v1.y); o[6] = f2bf(v1.z); o[7] = f2bf(v1.w);
  } else {
    o[0] = 0; o[1] = 0; o[2] = 0; o[3] = 0; o[4] = 0; o[5] = 0; o[6] = 0; o[7] = 0;
  }
  *(us8*)(dst + ((size_t)(m * HPAD + r) * CDIM + c8 * 8)) = o;
}

__device__ __forceinline__ void cvt8_colpad(const float* __restrict__ src,
                                            us* __restrict__ dst, int idx) {
  int r = idx / CH8_CPR, c8 = idx - r * CH8_CPR;
  int c = c8 * 8;
  us8 o;
  if (c < HRAW) {   // HRAW = 2744 = 343*8 -> chunk fully valid or fully pad
    const float4* p = (const float4*)(src + (size_t)r * HRAW + c);
    float4 v0 = p[0], v1 = p[1];
    o[0] = f2bf(v0.x); o[1] = f2bf(v0.y); o[2] = f2bf(v0.z); o[3] = f2bf(v0.w);
    o[4] = f2bf(v1.x); o[5] = f2bf(v1.y); o[6] = f2bf(v1.z); o[7] = f2bf(v1.w);
  } else {
    o[0] = 0; o[1] = 0; o[2] = 0; o[3] = 0; o[4] = 0; o[5] = 0; o[6] = 0; o[7] = 0;
  }
  *(us8*)(dst + (size_t)r * HPAD + c) = o;
}

// ---------------- gating (standalone, first) ----------------
__global__ void __launch_bounds__(256) gate_kernel(const float* __restrict__ x,
                                                   const float* __restrict__ gw,
                                                   us* __restrict__ xb,
                                                   int* __restrict__ tki,
                                                   float* __restrict__ tkw,
                                                   float* __restrict__ probs) {
  const int wv = threadIdx.x >> 6, lane = threadIdx.x & 63;
  const int s = blockIdx.x * 4 + wv;
  const float4* xs4 = (const float4*)(x + (size_t)s * CDIM);
  float acc[8] = {0, 0, 0, 0, 0, 0, 0, 0};
#pragma unroll
  for (int j = 0; j < 4; j++) {
    float4 v = xs4[lane * 4 + j];
    int c = lane * 16 + j * 4;
    us4 ov;
    ov.x = f2bf(v.x); ov.y = f2bf(v.y); ov.z = f2bf(v.z); ov.w = f2bf(v.w);
    *(us4*)(xb + (size_t)s * CDIM + c) = ov;
#pragma unroll
    for (int ee = 0; ee < 8; ee++) {
      const float* g = gw + ee * CDIM + c;
      acc[ee] += v.x * g[0] + v.y * g[1] + v.z * g[2] + v.w * g[3];
    }
  }
#pragma unroll
  for (int ee = 0; ee < 8; ee++) {
#pragma unroll
    for (int off = 32; off > 0; off >>= 1) acc[ee] += __shfl_xor(acc[ee], off, 64);
  }
  if (lane == 0) {
    float mx = acc[0];
    for (int ee = 1; ee < 8; ee++) mx = fmaxf(mx, acc[ee]);
    float p[8], sm = 0.f;
    for (int ee = 0; ee < 8; ee++) { p[ee] = expf(acc[ee] - mx); sm += p[ee]; }
    float inv = 1.f / sm;
    for (int ee = 0; ee < 8; ee++) probs[s * 8 + ee] = p[ee] * inv;
    int i0 = 0; float b0 = p[0];
    for (int ee = 1; ee < 8; ee++) if (p[ee] > b0) { b0 = p[ee]; i0 = ee; }
    int i1 = -1; float b1 = -1.f;
    for (int ee = 0; ee < 8; ee++) if (ee != i0 && p[ee] > b1) { b1 = p[ee]; i1 = ee; }
    float rw0 = b0 * inv, rw1 = b1 * inv;
    float den = 1.f / (rw0 + rw1);
    tki[2 * s] = i0; tki[2 * s + 1] = i1;
    tkw[2 * s] = rw0 * den; tkw[2 * s + 1] = rw1 * den;
  }
}

// ---------------- cvt(w1,w2,sw1,sw2) us8 with build fused as block 0 -----------
#define CVTAB_BLKS 2048
#define AB8_W1   (8 * CH8_RP1)
#define AB8_W2   (AB8_W1 + 8 * CH8_RP1)
#define AB8_SW1  (AB8_W2 + CH8_RP1)
#define AB8_SW2  (AB8_SW1 + CH8_RP1)

__global__ void __launch_bounds__(512) cvtab_build_kernel(
    const float* __restrict__ w1, const float* __restrict__ w2,
    const float* __restrict__ sw1, const float* __restrict__ sw2,
    us* __restrict__ w1b, us* __restrict__ w2b,
    us* __restrict__ sw1b, us* __restrict__ sw2b,
    const int* __restrict__ tki, const float* __restrict__ tkw,
    const float* __restrict__ probs, int* __restrict__ meta,
    int* __restrict__ pairtok, float* __restrict__ pairw,
    int* __restrict__ invmap, int* __restrict__ tile_expert,
    float* __restrict__ aux_out) {
  if (blockIdx.x == 0) {
    const int tid = threadIdx.x, lane = tid & 63, wv = tid >> 6;
    __shared__ int s_cnt[EXP];
    __shared__ int s_amc[EXP];
    __shared__ float s_imp[EXP];
    {
      const int e = wv;
      int c_cnt = 0, c_amc = 0;
      float imp = 0.f;
      for (int s0 = 0; s0 < S_TOK; s0 += 64) {
        int s = s0 + lane;
        int i0 = tki[2 * s], i1 = tki[2 * s + 1];
        c_cnt += (i0 == e) || (i1 == e);
        c_amc += (i0 == e);
        imp += probs[s * 8 + e];
      }
#pragma unroll
      for (int off = 32; off > 0; off >>= 1) {
        c_cnt += __shfl_xor(c_cnt, off, 64);
        c_amc += __shfl_xor(c_amc, off, 64);
        imp   += __shfl_xor(imp, off, 64);
      }
      if (lane == 0) { s_cnt[e] = c_cnt; s_amc[e] = c_amc; s_imp[e] = imp; }
    }
    __syncthreads();
    int pad[EXP], start[EXP];
    int o = S_TOK;
#pragma unroll
    for (int j = 0; j < EXP; j++) {
      pad[j] = ((s_cnt[j] + 127) >> 7) << 7;
      start[j] = o;
      o += pad[j];
    }
    const int total = o;
    for (int r = tid; r < S_TOK; r += 512) { pairtok[r] = r; pairw[r] = 1.f; }
    {
      const int e = wv;
      int base = start[e];
      for (int s0 = 0; s0 < S_TOK; s0 += 64) {
        int s = s0 + lane;
        int i0 = tki[2 * s], i1 = tki[2 * s + 1];
        bool m0 = (i0 == e), m1 = (i1 == e);
        bool mm = m0 || m1;
        unsigned long long mk = __ballot(mm);
        if (mm) {
          int pos = base + __popcll(mk & ((1ull << lane) - 1ull));
          pairtok[pos] = s;
          pairw[pos] = m0 ? tkw[2 * s] : tkw[2 * s + 1];
          invmap[2 * s + (m0 ? 0 : 1)] = pos;
        }
        base += __popcll(mk);
      }
      for (int r = base + lane; r < start[e] + pad[e]; r += 64) {
        pairtok[r] = -1; pairw[r] = 0.f;
      }
    }
    if (tid < 128) {
      int ex = 8;
      if (tid >= 32) {
        int rr = tid * 128;
#pragma unroll
        for (int j = 0; j < EXP; j++)
          if (rr >= start[j] && rr < start[j] + pad[j]) ex = j;
      }
      tile_expert[tid] = ex;
    }
    if (tid == 0) {
      meta[0] = total >> 7;
      float a = 0.f;
      for (int j = 0; j < EXP; j++)
        a += (s_imp[j] * (1.f / 4096.f)) * ((float)s_amc[j] * (1.f / 4096.f));
      aux_out[0] = 8.f * a;
    }
    return;
  }
  for (int i = (blockIdx.x - 1) * 512 + threadIdx.x; i < AB8_SW2;
       i += (CVTAB_BLKS - 1) * 512) {
    if (i < AB8_W1)       cvt8_rowpad(w1,  w1b,  i);
    else if (i < AB8_W2)  cvt8_rowpad(w2,  w2b,  i - AB8_W1);
    else if (i < AB8_SW1) cvt8_rowpad(sw1, sw1b, i - AB8_W2);
    else                  cvt8_rowpad(sw2, sw2b, i - AB8_SW1);
  }
}

// ---------------- GEMM1: BK=64 single-buffer + w3/sw3 us8 cvt tail blocks ------
#define W3CVT_BLKS 1024
#define W38_CHUNKS (8 * CDIM * CH8_CPR)
#define W38_TOT    (W38_CHUNKS + CDIM * CH8_CPR)

__global__ void __launch_bounds__(256, 2) gemm1_kernel(
    const us* __restrict__ xb, const us* __restrict__ w1b, const us* __restrict__ w2b,
    const us* __restrict__ sw1b, const us* __restrict__ sw2b,
    const int* __restrict__ pairtok, const int* __restrict__ tile_expert,
    const int* __restrict__ meta, us* __restrict__ h,
    const float* __restrict__ w3, const float* __restrict__ sw3,
    us* __restrict__ w3b, us* __restrict__ sw3b) {
  if (blockIdx.x >= G1_BLKS) {
    for (int i = (blockIdx.x - G1_BLKS) * 256 + threadIdx.x; i < W38_TOT;
         i += W3CVT_BLKS * 256) {
      if (i < W38_CHUNKS) cvt8_colpad(w3,  w3b,  i);
      else                cvt8_colpad(sw3, sw3b, i - W38_CHUNKS);
    }
    return;
  }
  const int wgid = xcd_swz(blockIdx.x, G1_BLKS);
  const int mt = wgid % MAXTILES;
  if (mt >= meta[0]) return;
  const int row0 = mt * 128;
  const int n0 = (wgid / MAXTILES) * 128;
  const int e = tile_expert[mt];
  const us* B1 = (e == 8) ? sw1b : (w1b + (size_t)e * HPAD * CDIM);
  const us* B2 = (e == 8) ? sw2b : (w2b + (size_t)e * HPAD * CDIM);
  __shared__ __align__(16) us sA[128 * 64];
  __shared__ __align__(16) us sB1[128 * 64];
  __shared__ __align__(16) us sB2[128 * 64];
  const int tid = threadIdx.x, lane = tid & 63;
  const int wm = tid >> 7, wn = (tid >> 6) & 1;
  const int srow = tid >> 3;
  const int soct = (tid & 7) ^ (srow & 7);
  const us* gA[4];
  const us* gB1a[4];
  const us* gB2a[4];
#pragma unroll
  for (int j = 0; j < 4; j++) {
    int t = pairtok[row0 + j * 32 + srow]; if (t < 0) t = 0;
    gA[j]   = xb + (size_t)t * CDIM + soct * 8;
    gB1a[j] = B1 + (size_t)(n0 + j * 32 + srow) * CDIM + soct * 8;
    gB2a[j] = B2 + (size_t)(n0 + j * 32 + srow) * CDIM + soct * 8;
  }
  f32x4 au[4][4], av[4][4];
#pragma unroll
  for (int m = 0; m < 4; m++)
#pragma unroll
    for (int n = 0; n < 4; n++)
#pragma unroll
      for (int r = 0; r < 4; r++) { au[m][n][r] = 0.f; av[m][n][r] = 0.f; }

  const int rl = lane & 15, fo = lane >> 4;
  const int x0 = ((0 + fo) ^ (rl & 7)) << 3;
  const int x1 = ((4 + fo) ^ (rl & 7)) << 3;
  for (int k0 = 0; k0 < CDIM; k0 += 64) {
#pragma unroll
    for (int j = 0; j < 4; j++) {
      gl16(gA[j] + k0,   &sA[(j * 256 + tid) * 8]);
      gl16(gB1a[j] + k0, &sB1[(j * 256 + tid) * 8]);
      gl16(gB2a[j] + k0, &sB2[(j * 256 + tid) * 8]);
    }
    __syncthreads();
#pragma unroll
    for (int ks = 0; ks < 2; ks++) {
      const int kx = ks ? x1 : x0;
      bf16x8 a[4], b1[4], b2[4];
#pragma unroll
      for (int m = 0; m < 4; m++)
        a[m] = *(const bf16x8*)&sA[(wm * 64 + m * 16 + rl) * 64 + kx];
#pragma unroll
      for (int n = 0; n < 4; n++) {
        b1[n] = *(const bf16x8*)&sB1[(wn * 64 + n * 16 + rl) * 64 + kx];
        b2[n] = *(const bf16x8*)&sB2[(wn * 64 + n * 16 + rl) * 64 + kx];
      }
#pragma unroll
      for (int m = 0; m < 4; m++)
#pragma unroll
        for (int n = 0; n < 4; n++) {
          au[m][n] = __builtin_amdgcn_mfma_f32_16x16x32_bf16(a[m], b1[n], au[m][n], 0, 0, 0);
          av[m][n] = __builtin_amdgcn_mfma_f32_16x16x32_bf16(a[m], b2[n], av[m][n], 0, 0, 0);
        }
    }
    __syncthreads();
  }
  const int rb = (lane >> 4) * 4, cb = lane & 15;
#pragma unroll
  for (int m = 0; m < 4; m++)
#pragma unroll
    for (int n = 0; n < 4; n++)
#pragma unroll
      for (int r = 0; r < 4; r++) {
        int row = row0 + wm * 64 + m * 16 + rb + r;
        int col = n0 + wn * 64 + n * 16 + cb;
        float u = au[m][n][r], v = av[m][n][r];
        float sg = 1.f / (1.f + __expf(-u));
        h[(size_t)row * HPAD + col] = f2bf(u * sg * v);
      }
}

// ---------------- GEMM2: eo = h @ w3^T, block 128x256, BK=64, bf16 out --------
__global__ void __launch_bounds__(256, 2) gemm2_kernel(
    const us* __restrict__ h, const us* __restrict__ w3b, const us* __restrict__ sw3b,
    const int* __restrict__ tile_expert, const int* __restrict__ meta,
    us* __restrict__ eo) {
  const int wgid = xcd_swz(blockIdx.x, MAXTILES * NSLICE2);
  const int mt = wgid % MAXTILES;
  if (mt >= meta[0]) return;
  const int n0 = (wgid / MAXTILES) * 256;
  const int e = tile_expert[mt];
  const us* B = (e == 8) ? sw3b : (w3b + (size_t)e * CDIM * HPAD);
  const int row0 = mt * 128;
  __shared__ __align__(16) us sA[128 * 64];
  __shared__ __align__(16) us sB[256 * 64];
  const int tid = threadIdx.x, lane = tid & 63;
  const int wm = tid >> 7, wn = (tid >> 6) & 1;
  const int srow = tid >> 3;
  const int soct = (tid & 7) ^ (srow & 7);
  const us* gA[4];
  const us* gB[8];
#pragma unroll
  for (int j = 0; j < 4; j++)
    gA[j] = h + (size_t)(row0 + j * 32 + srow) * HPAD + soct * 8;
#pragma unroll
  for (int j = 0; j < 8; j++)
    gB[j] = B + (size_t)(n0 + j * 32 + srow) * HPAD + soct * 8;
  f32x4 ac[4][8];
#pragma unroll
  for (int m = 0; m < 4; m++)
#pragma unroll
    for (int n = 0; n < 8; n++)
#pragma unroll
      for (int r = 0; r < 4; r++) ac[m][n][r] = 0.f;

  const int rl = lane & 15, fo = lane >> 4;
  const int x0 = ((0 + fo) ^ (rl & 7)) << 3;
  const int x1 = ((4 + fo) ^ (rl & 7)) << 3;
  for (int k0 = 0; k0 < HPAD; k0 += 64) {
#pragma unroll
    for (int j = 0; j < 4; j++)
      gl16(gA[j] + k0, &sA[(j * 256 + tid) * 8]);
#pragma unroll
    for (int j = 0; j < 8; j++)
      gl16(gB[j] + k0, &sB[(j * 256 + tid) * 8]);
    __syncthreads();
#pragma unroll
    for (int ks = 0; ks < 2; ks++) {
      const int kx = ks ? x1 : x0;
      bf16x8 a[4], b[8];
#pragma unroll
      for (int m = 0; m < 4; m++)
        a[m] = *(const bf16x8*)&sA[(wm * 64 + m * 16 + rl) * 64 + kx];
#pragma unroll
      for (int n = 0; n < 8; n++)
        b[n] = *(const bf16x8*)&sB[(wn * 128 + n * 16 + rl) * 64 + kx];
#pragma unroll
      for (int m = 0; m < 4; m++)
#pragma unroll
        for (int n = 0; n < 8; n++)
          ac[m][n] = __builtin_amdgcn_mfma_f32_16x16x32_bf16(a[m], b[n], ac[m][n], 0, 0, 0);
    }
    __syncthreads();
  }
  const int rb = (lane >> 4) * 4, cb = lane & 15;
#pragma unroll
  for (int m = 0; m < 4; m++)
#pragma unroll
    for (int n = 0; n < 8; n++)
#pragma unroll
      for (int r = 0; r < 4; r++) {
        int row = row0 + wm * 64 + m * 16 + rb + r;
        int col = n0 + wn * 128 + n * 16 + cb;
        eo[(size_t)row * CDIM + col] = f2bf(ac[m][n][r]);
      }
}

// ---------------- combine (bf16 eo) ----------------
__global__ void __launch_bounds__(256) combine_kernel(const us* __restrict__ eo,
                                                      const int* __restrict__ invmap,
                                                      const float* __restrict__ pairw,
                                                      float* __restrict__ out) {
  const int s = blockIdx.x;
  const int c = threadIdx.x * 4;
  const int j0 = invmap[2 * s], j1 = invmap[2 * s + 1];
  const float w0 = pairw[j0], w1 = pairw[j1];
  us4 a = *(const us4*)(eo + (size_t)s * CDIM + c);
  us4 b = *(const us4*)(eo + (size_t)j0 * CDIM + c);
  us4 d = *(const us4*)(eo + (size_t)j1 * CDIM + c);
  float4 o;
  o.x = bf2f(a.x) + w0 * bf2f(b.x) + w1 * bf2f(d.x);
  o.y = bf2f(a.y) + w0 * bf2f(b.y) + w1 * bf2f(d.y);
  o.z = bf2f(a.z) + w0 * bf2f(b.z) + w1 * bf2f(d.z);
  o.w = bf2f(a.w) + w0 * bf2f(b.w) + w1 * bf2f(d.w);
  *(float4*)(out + (size_t)s * CDIM + c) = o;
}

extern "C" void kernel_launch(void* const* d_in, const int* in_sizes, int n_in,
                              void* d_out, int out_size, void* d_ws, size_t ws_size,
                              hipStream_t stream) {
  const float* x   = (const float*)d_in[0];
  const float* gw  = (const float*)d_in[1];
  const float* w1  = (const float*)d_in[2];
  const float* w2  = (const float*)d_in[3];
  const float* w3  = (const float*)d_in[4];
  const float* sw1 = (const float*)d_in[5];
  const float* sw2 = (const float*)d_in[6];
  const float* sw3 = (const float*)d_in[7];
  float* out = (float*)d_out;
  char* ws = (char*)d_ws;
  size_t off = 0;
  auto take = [&](size_t bytes) -> char* {
    char* p = ws + off;
    off = (off + bytes + 255) & ~(size_t)255;
    return p;
  };
  us* xb    = (us*)take((size_t)S_TOK * CDIM * 2);
  us* w1b   = (us*)take((size_t)EXP * HPAD * CDIM * 2);
  us* w2b   = (us*)take((size_t)EXP * HPAD * CDIM * 2);
  us* w3b   = (us*)take((size_t)EXP * CDIM * HPAD * 2);
  us* sw1b  = (us*)take((size_t)HPAD * CDIM * 2);
  us* sw2b  = (us*)take((size_t)HPAD * CDIM * 2);
  us* sw3b  = (us*)take((size_t)CDIM * HPAD * 2);
  us* hbuf  = (us*)take((size_t)MAXROWS * HPAD * 2);
  us* eo    = (us*)take((size_t)MAXROWS * CDIM * 2);
  int* pairtok = (int*)take(MAXROWS * 4);
  float* pairw = (float*)take(MAXROWS * 4);
  int* invmap  = (int*)take(S_TOK * 2 * 4);
  int* tile_expert = (int*)take(128 * 4);
  int* tki = (int*)take(S_TOK * 2 * 4);
  float* tkw = (float*)take(S_TOK * 2 * 4);
  float* probs = (float*)take(S_TOK * EXP * 4);
  int* meta = (int*)take(256);
  if (off > ws_size) {
    fprintf(stderr, "MoE kernel: ws too small, need %zu got %zu\n", off, ws_size);
    return;
  }
  gate_kernel<<<S_TOK / 4, 256, 0, stream>>>(x, gw, xb, tki, tkw, probs);
  cvtab_build_kernel<<<CVTAB_BLKS, 512, 0, stream>>>(
      w1, w2, sw1, sw2, w1b, w2b, sw1b, sw2b,
      tki, tkw, probs, meta, pairtok, pairw, invmap, tile_expert,
      out + (size_t)S_TOK * CDIM);
  gemm1_kernel<<<G1_BLKS + W3CVT_BLKS, 256, 0, stream>>>(
      xb, w1b, w2b, sw1b, sw2b, pairtok, tile_expert, meta, hbuf,
      w3, sw3, w3b, sw3b);
  gemm2_kernel<<<MAXTILES * NSLICE2, 256, 0, stream>>>(
      hbuf, w3b, sw3b, tile_expert, meta, eo);
  combine_kernel<<<S_TOK, 256, 0, stream>>>(eo, invmap, pairw, out);
}